// Round 5
// baseline (787.585 us; speedup 1.0000x reference)
//
#include <hip/hip_runtime.h>
#include <math.h>

#define NN 1000
#define INF_ 32
#define H 128
#define M 128
#define DEG 16
#define PP 2
#define OUTF 10
#define MAXM (10 * NN)        // scan length; head <= MAXM
#define QCAP (MAXM + DEG)     // only entries < MAXM are ever read
#define NSLOT (MAXM + 128)    // nmbuf rows: nstart + total procs
#define NT 1024
#define NWAVE 16
#define CH 32                 // rows per chunk (= NT/32)
#define WROW 264              // padded halves per X/weight row (256+8)
#define NROW 136              // padded halves per NSh row (128+8)

typedef _Float16 half8 __attribute__((ext_vector_type(8)));
typedef float floatx4 __attribute__((ext_vector_type(4)));

// LDS-only barrier: publishes LDS writes without draining global (vmcnt) queue.
__device__ __forceinline__ void bar_lds() {
    asm volatile("s_waitcnt lgkmcnt(0)\n\ts_barrier" ::: "memory");
}

// ws: feats_h[NN*H] f16 | finalv[NN*H] f32 | nmbuf_h[NSLOT*M] f16
//     | wnsB f16 | wnmB f16 | (qpack region unused: queue lives in LDS)

__global__ __launch_bounds__(128)
void init_kernel(const float* __restrict__ xa, const float* __restrict__ fm,
                 const float* __restrict__ enc_w, const float* __restrict__ enc_b,
                 const int* __restrict__ nstart_p,
                 _Float16* __restrict__ feats_h, float* __restrict__ finalv,
                 _Float16* __restrict__ nmbuf_h) {
    int b = blockIdx.x, t = threadIdx.x;
    float acc = enc_b[t];
    const float* xr = xa + b * INF_;
#pragma unroll
    for (int k = 0; k < INF_; ++k) acc += xr[k] * enc_w[k * H + t];
    feats_h[b * H + t] = (_Float16)acc;     // same rounding point as before
    finalv[b * H + t] = 0.0f;
    if (b < nstart_p[0]) nmbuf_h[(size_t)b * M + t] = (_Float16)fm[b * M + t];
}

// Pack weights fp16 transposed [n][k] with +8 pad: wB[n*WROW+k] = w[k][n].
__global__ __launch_bounds__(256)
void pack_kernel(const float* __restrict__ ns_w, const float* __restrict__ nm_w,
                 _Float16* __restrict__ wnsB, _Float16* __restrict__ wnmB) {
    const int idx = blockIdx.x * 256 + threadIdx.x;   // 128*WROW
    if (idx >= 128 * WROW) return;
    const int n = idx / WROW, k = idx % WROW;
    wnsB[idx] = (k < 256) ? (_Float16)ns_w[k * H + n] : (_Float16)0.0f;
    wnmB[idx] = (k < 256) ? (_Float16)nm_w[k * M + n] : (_Float16)0.0f;
}

// Rank-decomposed sequential ACT loop; MFMA matvecs with REGISTER-RESIDENT
// weight B-fragments; LDS-only fine barriers; LDS message queue.
// R4: NT=1024 (16 waves = 4/SIMD) with 32-row chunks. Per-thread per-chunk
// work unchanged vs R3 (waves 0-7 rows 0-15, waves 8-15 rows 16-31);
// chunk count halves; 4 waves/SIMD hide the LDS/MFMA dependency chains
// that were ~60% stall at 2 waves/SIMD. fv prefetch-across-chunks dropped
// (loads at chunk start, used at epilogue) to stay within 128 VGPR.
__global__ __launch_bounds__(NT, 1)
void seq_kernel(const int* __restrict__ neighbors,
                const float* __restrict__ ns_b, const float* __restrict__ nm_b,
                const float* __restrict__ act_w, const float* __restrict__ act_b,
                const float* __restrict__ dec_w, const float* __restrict__ dec_b,
                const int* __restrict__ nstart_p,
                const _Float16* __restrict__ wnsB, const _Float16* __restrict__ wnmB,
                _Float16* __restrict__ feats_h, float* __restrict__ finalv,
                _Float16* __restrict__ nmbuf_h, unsigned int* __restrict__ qpack_unused,
                float* __restrict__ out) {
    __shared__ __align__(16) _Float16 s_Xh[CH * WROW];   // 16896 B
    __shared__ __align__(16) _Float16 s_NSh[CH * NROW];  // 8704 B
    __shared__ unsigned int s_q[QCAP];                   // 40064 B (LDS queue)
    __shared__ float s_tact[NN];                         // 4000 B
    __shared__ int   s_mark[NN];                         // 4000 B (order/readout overlay)
    __shared__ float s_actw[H + M];
    __shared__ float s_nsb[H];
    __shared__ float s_nmb[M];
    __shared__ float s_rna[CH];
    __shared__ unsigned short s_rnode[NT];               // rows, rank order
    __shared__ unsigned short s_rslot[NT];               // msg slot per row
    __shared__ unsigned int  s_enq[NT];                  // node|newslot<<16 per entry
    __shared__ unsigned char s_flag[NT];
    __shared__ int s_wc[NWAVE];
    __shared__ int s_cnt;

    short* s_order = (short*)s_mark;                     // overlay: mark[0..511] = 1024 shorts
    float* s_g  = (float*)(s_mark + 512);                // overlay: readout only
    float* s_lg = (float*)(s_mark + 512 + 128);

    const int t = threadIdx.x;
    const int lane = t & 63, wid = t >> 6;               // wid 0..15
    const int quad = lane >> 4, lm = lane & 15;
    const int rowblk = wid >> 3;                         // 0: rows 0-15, 1: rows 16-31
    const int colw = ((wid & 7) << 4) + lm;              // this thread's output col
    const int sg = t & 31;                               // gate sub-lane
    const int r32 = t >> 5, c8 = t & 31;                 // staging coords (32x32)
    const int nstart = nstart_p[0];

    // ---- one-time: weight B-fragments into registers (loop-invariant) ----
    half8 wbn[8], wbm[8];
#pragma unroll
    for (int c = 0; c < 8; ++c) {
        wbn[c] = *(const half8*)(wnsB + (size_t)colw * WROW + (c << 5) + (quad << 3));
        wbm[c] = *(const half8*)(wnmB + (size_t)colw * WROW + (c << 5) + (quad << 3));
    }

    for (int i = t; i < NN; i += NT) { s_tact[i] = 0.0f; s_mark[i] = 0x7fffffff; }
    for (int i = t; i < nstart; i += NT) s_q[i] = (unsigned)i | ((unsigned)i << 16);
    if (t < H + M) s_actw[t] = act_w[t];
    if (t < H) { s_nsb[t] = ns_b[t]; s_nmb[t] = nm_b[t]; }
    const float actb = act_b[0];
    __syncthreads();

    int head = 0, tail = nstart, gbase = nstart;
    for (;;) {
        const int lim = min(tail, MAXM);
        if (head >= lim) break;
        const int W = min(NT, lim - head);

        // ---- classify; clear flags; repair order-overlaid mark ----
        int node = 0, slotv = 0; bool remaining = false;
        if (t < W) {
            const unsigned v = s_q[head + t];
            node = (int)(v & 0xffffu);
            slotv = (int)(v >> 16);
            remaining = (s_tact[node] <= 1.0f - 1e-7f);
        }
        s_flag[t] = 0;
        if (t < 512) s_mark[t] = 0x7fffffff;             // repair overlay region
        bar_lds();                                       // B1

        // ---------------- rank rounds ----------------
        int base = 0;
        for (;;) {
            const bool rem2 = remaining && (s_tact[node] <= 1.0f - 1e-7f);
            if (rem2) atomicMin(&s_mark[node], t);
            if (t == 0) s_cnt = 0;
            bar_lds();                                   // R1
            const bool win = rem2 && (s_mark[node] == t);
            const unsigned long long mw = __ballot(win);
            const int wcnt = __popcll(mw);
            int wbase = 0;
            if (lane == 0 && wcnt) wbase = atomicAdd(&s_cnt, wcnt);
            wbase = __shfl(wbase, 0, 64);
            const int wrank = wbase + __popcll(mw & ((1ull << lane) - 1ull));
            if (win) {
                s_rnode[wrank] = (unsigned short)node;
                s_rslot[wrank] = (unsigned short)slotv;
                s_enq[t] = (unsigned)node | ((unsigned)(gbase + base + wrank) << 16);
                s_flag[t] = 1;
            }
            remaining = rem2 && !win;
            bar_lds();                                   // R3: rnode/rslot/cnt ready
            // mark reset: barrier-separated from win-check reads (race-free);
            // next atomicMin use is after R7 (full sync).
            if (rem2) s_mark[node] = 0x7fffffff;
            const int Pr = s_cnt;
            if (Pr == 0) break;

            // ---- prefetch chunk 0 X row (uint4) ----
            uint4 px;
            {
                const int rr = min(r32, Pr - 1);
                const int nr = (int)s_rnode[rr];
                const int sl = (int)s_rslot[rr];
                px = (c8 < 16)
                    ? ((const uint4*)(feats_h + (size_t)nr * H))[c8]
                    : ((const uint4*)(nmbuf_h + (size_t)sl * M))[c8 - 16];
            }
            // ---- chunks of CH rows, software-pipelined staging ----
            for (int c0 = 0; c0 < Pr; c0 += CH) {
                const int Pc = min(CH, Pr - c0);
                *(uint4*)(s_Xh + r32 * WROW + (c8 << 3)) = px;
                // gate partial from px REGISTERS (bitwise == LDS-read path)
                float zred;
                {
                    const half8 hv = *(const half8*)&px;
                    float aw[8];
#pragma unroll
                    for (int j = 0; j < 8; ++j) aw[j] = s_actw[sg * 8 + j];
                    float p = 0.0f;
#pragma unroll
                    for (int j = 0; j < 8; ++j) p += (float)hv[j] * aw[j];
#pragma unroll
                    for (int off = 16; off > 0; off >>= 1) p += __shfl_down(p, off, 32);
                    zred = p;                            // valid in sg==0
                }
                bar_lds();                               // A: Xh(c) ready
                const bool hasnext = (c0 + CH) < Pr;
                uint4 pxn;
                if (hasnext) {                           // issue next-chunk staging loads
                    const int rr = min(c0 + CH + r32, Pr - 1);
                    const int nr = (int)s_rnode[rr];
                    const int sl = (int)s_rslot[rr];
                    pxn = (c8 < 16)
                        ? ((const uint4*)(feats_h + (size_t)nr * H))[c8]
                        : ((const uint4*)(nmbuf_h + (size_t)sl * M))[c8 - 16];
                }
                // per-thread output rows: r = rowblk*16 + quad*4 + i
                int nr4[4]; float fv[4];
#pragma unroll
                for (int i = 0; i < 4; ++i) {
                    const int r = (rowblk << 4) + (quad << 2) + i;
                    nr4[i] = (int)s_rnode[min(c0 + r, Pr - 1)];
                    fv[i] = finalv[(size_t)nr4[i] * H + colw];   // used at epilogue
                }
                // gate finalize: 1 thread/row, spread across waves; overlaps MFMA-1.
                if (sg == 0 && r32 < Pc) {
                    const float z = zred + actb;
                    const float cnd = 1.0f / (1.0f + expf(-z));
                    const int nr = (int)s_rnode[c0 + r32];
                    const float ta = s_tact[nr];
                    const float na = (ta + cnd > 1.0f) ? (1.0f - ta) : cnd;
                    s_rna[r32] = na;
                    s_tact[nr] = ta + na;
                }
                // phase 1 MFMA: ns (K=256) + nm msg-half (K=128..256); B from regs
                floatx4 accn = {0.0f, 0.0f, 0.0f, 0.0f};
                floatx4 accm = {0.0f, 0.0f, 0.0f, 0.0f};
                {
                    const _Float16* xrow = s_Xh + ((rowblk << 4) + lm) * WROW + (quad << 3);
                    half8 a[8];
#pragma unroll
                    for (int c = 0; c < 8; ++c) a[c] = *(const half8*)(xrow + (c << 5));
#pragma unroll
                    for (int c = 0; c < 8; ++c)
                        accn = __builtin_amdgcn_mfma_f32_16x16x32_f16(
                            a[c], wbn[c], accn, 0, 0, 0);
#pragma unroll
                    for (int c = 4; c < 8; ++c)
                        accm = __builtin_amdgcn_mfma_f32_16x16x32_f16(
                            a[c], wbm[c], accm, 0, 0, 0);
                }
                float nsv[4];
                {
                    const float nsb_c = s_nsb[colw];
#pragma unroll
                    for (int i = 0; i < 4; ++i) {
                        const int r = (rowblk << 4) + (quad << 2) + i;
                        nsv[i] = fmaxf(accn[i] + nsb_c, 0.0f);
                        if (r < Pc) {
                            s_NSh[r * NROW + colw] = (_Float16)nsv[i];
                            feats_h[(size_t)nr4[i] * H + colw] = (_Float16)nsv[i];
                        }
                    }
                }
                bar_lds();                               // B: Xh reads done; NSh+rna ready
                float na4[4];
#pragma unroll
                for (int i = 0; i < 4; ++i) na4[i] = s_rna[(rowblk << 4) + (quad << 2) + i];
                // phase 2 MFMA: nm ns-half (K=0..128); B from regs; nmbuf store
                {
                    const _Float16* nrow = s_NSh + ((rowblk << 4) + lm) * NROW + (quad << 3);
#pragma unroll
                    for (int c = 0; c < 4; ++c)
                        accm = __builtin_amdgcn_mfma_f32_16x16x32_f16(
                            *(const half8*)(nrow + (c << 5)), wbm[c], accm, 0, 0, 0);
                }
                {
                    const float nmb_c = s_nmb[colw];
#pragma unroll
                    for (int i = 0; i < 4; ++i) {
                        const int r = (rowblk << 4) + (quad << 2) + i;
                        if (r < Pc)
                            nmbuf_h[(size_t)(gbase + base + c0 + r) * M + colw] =
                                (_Float16)(accm[i] + nmb_c);
                    }
                }
                // epilogue: finalv via early-loaded values (exact += semantics)
#pragma unroll
                for (int i = 0; i < 4; ++i) {
                    const int r = (rowblk << 4) + (quad << 2) + i;
                    if (r < Pc)
                        finalv[(size_t)nr4[i] * H + colw] = fv[i] + nsv[i] * na4[i];
                }
                if (hasnext) px = pxn;
            }
            base += Pr;
            __syncthreads();       // R7 (full): drain feats/nmbuf/finalv stores
        }

        // -------- enqueue (queue order via prefix over flags) --------
        const bool pf = (s_flag[t] != 0);
        const unsigned long long mf = __ballot(pf);
        if (lane == 0) s_wc[wid] = __popcll(mf);
        bar_lds();                                       // B3
        int T = 0, prec = 0;
#pragma unroll
        for (int w = 0; w < NWAVE; ++w) { T += s_wc[w]; prec += (w < wid) ? s_wc[w] : 0; }
        if (T > 0) {
            if (pf) s_order[prec + __popcll(mf & ((1ull << lane) - 1ull))] = (short)t;
            bar_lds();                                   // B4
            for (int idx = t; idx < T * DEG; idx += NT) {
                const int e = (int)s_order[idx >> 4];
                const unsigned v = s_enq[e];
                const int nd = (int)(v & 0xffffu);
                const unsigned slot = v >> 16;
                const int q = tail + idx;
                if (q < QCAP)
                    s_q[q] = (unsigned)neighbors[nd * DEG + (idx & 15)] | (slot << 16);
            }
        }
        tail += DEG * T;
        gbase += T;
        head += W;
        bar_lds();                                       // B5 (LDS-only): s_q visible
    }

    // ---- readout (g/lg overlaid on dead mark region) ----
    if (t < H) {
        float g0 = 0, g1 = 0, g2 = 0, g3 = 0;
        for (int n = 0; n < NN; n += 4) {
            g0 += finalv[(n + 0) * H + t];
            g1 += finalv[(n + 1) * H + t];
            g2 += finalv[(n + 2) * H + t];
            g3 += finalv[(n + 3) * H + t];
        }
        s_g[t] = (g0 + g1) + (g2 + g3);
    }
    __syncthreads();
    if (t < PP * OUTF) {
        const int pp = t / OUTF, o = t % OUTF;
        float acc = dec_b[pp * OUTF + o];
        for (int h = 0; h < H; ++h) acc += s_g[h] * dec_w[(pp * H + h) * OUTF + o];
        s_lg[t] = acc;
    }
    __syncthreads();
    if (t < PP * OUTF) {
        const int pp = t / OUTF;
        float mx = -INFINITY;
        for (int o = 0; o < OUTF; ++o) mx = fmaxf(mx, s_lg[pp * OUTF + o]);
        float s = 0.0f;
        for (int o = 0; o < OUTF; ++o) s += expf(s_lg[pp * OUTF + o] - mx);
        out[t] = s_lg[t] - (mx + logf(s));
    }
}

extern "C" void kernel_launch(void* const* d_in, const int* in_sizes, int n_in,
                              void* d_out, int out_size, void* d_ws, size_t ws_size,
                              hipStream_t stream) {
    const float* xa        = (const float*)d_in[0];
    const float* fm        = (const float*)d_in[1];
    const int*   neighbors = (const int*)  d_in[2];
    const int*   nstart_p  = (const int*)  d_in[3];
    const float* enc_w     = (const float*)d_in[4];
    const float* enc_b     = (const float*)d_in[5];
    const float* ns_w      = (const float*)d_in[6];
    const float* ns_b      = (const float*)d_in[7];
    const float* nm_w      = (const float*)d_in[8];
    const float* nm_b      = (const float*)d_in[9];
    const float* act_w     = (const float*)d_in[10];
    const float* act_b     = (const float*)d_in[11];
    const float* dec_w     = (const float*)d_in[12];
    const float* dec_b     = (const float*)d_in[13];
    float* out = (float*)d_out;

    char* w = (char*)d_ws;
    _Float16* feats_h = (_Float16*)w;                 w += (size_t)NN * H * 2;
    float*    finalv  = (float*)w;                    w += (size_t)NN * H * 4;
    _Float16* nmbuf_h = (_Float16*)w;                 w += (size_t)NSLOT * M * 2;
    _Float16* wnsB    = (_Float16*)w;                 w += (size_t)128 * WROW * 2;
    _Float16* wnmB    = (_Float16*)w;                 w += (size_t)128 * WROW * 2;
    unsigned int* qpack = (unsigned int*)w;           // unused (LDS queue)

    init_kernel<<<NN, 128, 0, stream>>>(xa, fm, enc_w, enc_b, nstart_p,
                                        feats_h, finalv, nmbuf_h);
    pack_kernel<<<132, 256, 0, stream>>>(ns_w, nm_w, wnsB, wnmB);
    seq_kernel<<<1, NT, 0, stream>>>(neighbors, ns_b, nm_b,
                                     act_w, act_b, dec_w, dec_b, nstart_p,
                                     wnsB, wnmB,
                                     feats_h, finalv, nmbuf_h, qpack, out);
}

// Round 6
// 615.379 us; speedup vs baseline: 1.2798x; 1.2798x over previous
//
#include <hip/hip_runtime.h>
#include <math.h>

#define NN 1000
#define INF_ 32
#define H 128
#define M 128
#define DEG 16
#define PP 2
#define OUTF 10
#define MAXM (10 * NN)        // scan length; head <= MAXM
#define QCAP (MAXM + DEG)     // only entries < MAXM are ever read
#define NSLOT (MAXM + 128)    // nmbuf rows: nstart + total procs
#define NT 512
#define WQ (2 * NT)           // window size: 2 queue entries per thread
#define WROW 264              // padded halves per X/weight row (256+8)
#define NROW 136              // padded halves per NSh row (128+8)

typedef _Float16 half8 __attribute__((ext_vector_type(8)));
typedef float floatx4 __attribute__((ext_vector_type(4)));

// LDS-only barrier: publishes LDS writes without draining global (vmcnt) queue.
__device__ __forceinline__ void bar_lds() {
    asm volatile("s_waitcnt lgkmcnt(0)\n\ts_barrier" ::: "memory");
}

// ws: feats_h[NN*H] f16 | finalv[NN*H] f32 | nmbuf_h[NSLOT*M] f16
//     | wnsB f16 | wnmB f16 | (qpack region unused: queue lives in LDS)

__global__ __launch_bounds__(128)
void init_kernel(const float* __restrict__ xa, const float* __restrict__ fm,
                 const float* __restrict__ enc_w, const float* __restrict__ enc_b,
                 const int* __restrict__ nstart_p,
                 _Float16* __restrict__ feats_h, float* __restrict__ finalv,
                 _Float16* __restrict__ nmbuf_h) {
    int b = blockIdx.x, t = threadIdx.x;
    float acc = enc_b[t];
    const float* xr = xa + b * INF_;
#pragma unroll
    for (int k = 0; k < INF_; ++k) acc += xr[k] * enc_w[k * H + t];
    feats_h[b * H + t] = (_Float16)acc;     // same rounding point as before
    finalv[b * H + t] = 0.0f;
    if (b < nstart_p[0]) nmbuf_h[(size_t)b * M + t] = (_Float16)fm[b * M + t];
}

// Pack weights fp16 transposed [n][k] with +8 pad: wB[n*WROW+k] = w[k][n].
__global__ __launch_bounds__(256)
void pack_kernel(const float* __restrict__ ns_w, const float* __restrict__ nm_w,
                 _Float16* __restrict__ wnsB, _Float16* __restrict__ wnmB) {
    const int idx = blockIdx.x * 256 + threadIdx.x;   // 128*WROW
    if (idx >= 128 * WROW) return;
    const int n = idx / WROW, k = idx % WROW;
    wnsB[idx] = (k < 256) ? (_Float16)ns_w[k * H + n] : (_Float16)0.0f;
    wnmB[idx] = (k < 256) ? (_Float16)nm_w[k * M + n] : (_Float16)0.0f;
}

// Rank-decomposed sequential ACT loop; MFMA matvecs with REGISTER-RESIDENT
// weight B-fragments; LDS-only fine barriers; LDS message queue.
// R5: back to NT=512 (R4's 16 waves regressed: VGPR squeeze + lockstep
// barriers defeat TLP). Chunk loop rewritten as single-barrier software
// pipeline with double-buffered Xh/NSh/rna: iteration k runs
// stage(k+1) | prefetch(k+2) | phase2(k-1) || phase1(k) | finalize(k),
// then ONE bar_lds. Two independent MFMA chains per segment; barriers
// per chunk 2 -> 1. All arithmetic and store values bitwise-unchanged.
__global__ __launch_bounds__(NT, 1)
void seq_kernel(const int* __restrict__ neighbors,
                const float* __restrict__ ns_b, const float* __restrict__ nm_b,
                const float* __restrict__ act_w, const float* __restrict__ act_b,
                const float* __restrict__ dec_w, const float* __restrict__ dec_b,
                const int* __restrict__ nstart_p,
                const _Float16* __restrict__ wnsB, const _Float16* __restrict__ wnmB,
                _Float16* __restrict__ feats_h, float* __restrict__ finalv,
                _Float16* __restrict__ nmbuf_h, unsigned int* __restrict__ qpack_unused,
                float* __restrict__ out) {
    __shared__ __align__(16) _Float16 s_Xh[2][16 * WROW];   // 16896 B
    __shared__ __align__(16) _Float16 s_NSh[2][16 * NROW];  // 8704 B
    __shared__ unsigned int s_q[QCAP];                      // 40064 B (LDS queue)
    __shared__ float s_tact[NN];                            // 4000 B
    __shared__ int   s_mark[NN];                            // 4000 B (order/readout overlay)
    __shared__ float s_actw[H + M];
    __shared__ float s_nsb[H];
    __shared__ float s_nmb[M];
    __shared__ float s_rna[2][16];
    __shared__ unsigned short s_rnode[WQ];                  // rows, rank order
    __shared__ unsigned short s_rslot[WQ];                  // msg slot per row
    __shared__ unsigned int  s_enq[WQ];                     // node|newslot<<16 per entry
    __shared__ unsigned char s_flag[NT];                    // bit0: entry t, bit1: entry 512+t
    __shared__ int s_wc[8], s_wd[8];
    __shared__ int s_cnt;

    short* s_order = (short*)s_mark;                     // overlay: mark[0..511] = 1024 shorts
    float* s_g  = (float*)(s_mark + 512);                // overlay: readout only
    float* s_lg = (float*)(s_mark + 512 + 128);

    const int t = threadIdx.x;
    const int lane = t & 63, wid = t >> 6;
    const int quad = lane >> 4, lm = lane & 15;
    const int colw = (wid << 4) + lm;                    // this thread's output col
    const int sg = t & 31;                               // gate sub-lane
    const int r16 = t >> 5, c8 = t & 31;                 // staging coords (16x32)
    const int nstart = nstart_p[0];

    // ---- one-time: weight B-fragments into registers (loop-invariant) ----
    half8 wbn[8], wbm[8];
#pragma unroll
    for (int c = 0; c < 8; ++c) {
        wbn[c] = *(const half8*)(wnsB + (size_t)colw * WROW + (c << 5) + (quad << 3));
        wbm[c] = *(const half8*)(wnmB + (size_t)colw * WROW + (c << 5) + (quad << 3));
    }

    for (int i = t; i < NN; i += NT) { s_tact[i] = 0.0f; s_mark[i] = 0x7fffffff; }
    for (int i = t; i < nstart; i += NT) s_q[i] = (unsigned)i | ((unsigned)i << 16);
    if (t < H + M) s_actw[t] = act_w[t];
    if (t < H) { s_nsb[t] = ns_b[t]; s_nmb[t] = nm_b[t]; }
    const float actb = act_b[0];
    __syncthreads();
    const float nsb_c = s_nsb[colw];
    const float nmb_c = s_nmb[colw];
    float aw[8];
#pragma unroll
    for (int j = 0; j < 8; ++j) aw[j] = s_actw[sg * 8 + j];

    int head = 0, tail = nstart, gbase = nstart;
    for (;;) {
        const int lim = min(tail, MAXM);
        if (head >= lim) break;
        const int W = min(WQ, lim - head);

        // ---- classify both entries; clear flags; repair order-overlaid mark ----
        int nodeA = 0, slotA = 0; bool remA = false;
        int nodeB = 0, slotB = 0; bool remB = false;
        if (t < W) {
            const unsigned v = s_q[head + t];
            nodeA = (int)(v & 0xffffu);
            slotA = (int)(v >> 16);
            remA = (s_tact[nodeA] <= 1.0f - 1e-7f);
        }
        if (NT + t < W) {
            const unsigned v = s_q[head + NT + t];
            nodeB = (int)(v & 0xffffu);
            slotB = (int)(v >> 16);
            remB = (s_tact[nodeB] <= 1.0f - 1e-7f);
        }
        s_flag[t] = 0;
        s_mark[t] = 0x7fffffff;                          // repair overlay (t<512 region)
        bar_lds();                                       // B1

        // ---------------- rank rounds ----------------
        int base = 0;
        for (;;) {
            const bool rem2a = remA && (s_tact[nodeA] <= 1.0f - 1e-7f);
            const bool rem2b = remB && (s_tact[nodeB] <= 1.0f - 1e-7f);
            if (rem2a) atomicMin(&s_mark[nodeA], t);
            if (rem2b) atomicMin(&s_mark[nodeB], NT + t);
            if (t == 0) s_cnt = 0;
            bar_lds();                                   // R1
            const bool winA = rem2a && (s_mark[nodeA] == t);
            const bool winB = rem2b && (s_mark[nodeB] == NT + t);
            const unsigned long long ma = __ballot(winA);
            const unsigned long long mb = __ballot(winB);
            const int ca = __popcll(ma), cb = __popcll(mb);
            int wbase = 0;
            if (lane == 0 && (ca + cb)) wbase = atomicAdd(&s_cnt, ca + cb);
            wbase = __shfl(wbase, 0, 64);
            const unsigned long long below = (1ull << lane) - 1ull;
            if (winA) {
                const int wrank = wbase + __popcll(ma & below);
                s_rnode[wrank] = (unsigned short)nodeA;
                s_rslot[wrank] = (unsigned short)slotA;
                s_enq[t] = (unsigned)nodeA | ((unsigned)(gbase + base + wrank) << 16);
                s_flag[t] |= 1;
            }
            if (winB) {
                const int wrank = wbase + ca + __popcll(mb & below);
                s_rnode[wrank] = (unsigned short)nodeB;
                s_rslot[wrank] = (unsigned short)slotB;
                s_enq[NT + t] = (unsigned)nodeB | ((unsigned)(gbase + base + wrank) << 16);
                s_flag[t] |= 2;
            }
            remA = rem2a && !winA;
            remB = rem2b && !winB;
            bar_lds();                                   // R3: rnode/rslot/cnt ready
            // mark reset: barrier-separated from win-check reads (race-free);
            // next atomicMin use is after R7 (full sync).
            if (rem2a) s_mark[nodeA] = 0x7fffffff;
            if (rem2b) s_mark[nodeB] = 0x7fffffff;
            const int Pr = s_cnt;
            if (Pr == 0) break;

            // ================= single-barrier pipelined chunk loop =================
            // ---- prologue: chunk 0 ----
            uint4 px;
            {
                const int rr = min(r16, Pr - 1);
                const int nr = (int)s_rnode[rr];
                const int sl = (int)s_rslot[rr];
                px = (c8 < 16)
                    ? ((const uint4*)(feats_h + (size_t)nr * H))[c8]
                    : ((const uint4*)(nmbuf_h + (size_t)sl * M))[c8 - 16];
            }
            *(uint4*)(s_Xh[0] + r16 * WROW + (c8 << 3)) = px;
            float zredC;
            {
                const half8 hv = *(const half8*)&px;
                float p = 0.0f;
#pragma unroll
                for (int j = 0; j < 8; ++j) p += (float)hv[j] * aw[j];
#pragma unroll
                for (int off = 16; off > 0; off >>= 1) p += __shfl_down(p, off, 32);
                zredC = p;                               // valid in sg==0
            }
            if (Pr > 16) {                               // prefetch chunk 1
                const int rr = min(16 + r16, Pr - 1);
                const int nr = (int)s_rnode[rr];
                const int sl = (int)s_rslot[rr];
                px = (c8 < 16)
                    ? ((const uint4*)(feats_h + (size_t)nr * H))[c8]
                    : ((const uint4*)(nmbuf_h + (size_t)sl * M))[c8 - 16];
            }
            bar_lds();                                   // publish Xh[0]

            floatx4 accmP = {0.0f, 0.0f, 0.0f, 0.0f};
            float nsvP[4] = {0, 0, 0, 0};
            float fvP[4] = {0, 0, 0, 0};
            int   nrP[4] = {0, 0, 0, 0};
            int PcP = 0, sbP = 0;

            for (int c0 = 0; c0 < Pr; c0 += 16) {
                const int k = c0 >> 4;
                const int cur = k & 1, nxt = cur ^ 1;
                const int Pc = min(16, Pr - c0);
                const bool hasnext = (c0 + 16) < Pr;
                // stage chunk k+1 from px; gate-reduce it
                float zredN = 0.0f;
                if (hasnext) {
                    *(uint4*)(s_Xh[nxt] + r16 * WROW + (c8 << 3)) = px;
                    const half8 hv = *(const half8*)&px;
                    float p = 0.0f;
#pragma unroll
                    for (int j = 0; j < 8; ++j) p += (float)hv[j] * aw[j];
#pragma unroll
                    for (int off = 16; off > 0; off >>= 1) p += __shfl_down(p, off, 32);
                    zredN = p;
                }
                // prefetch chunk k+2
                if ((c0 + 32) < Pr) {
                    const int rr = min(c0 + 32 + r16, Pr - 1);
                    const int nr = (int)s_rnode[rr];
                    const int sl = (int)s_rslot[rr];
                    px = (c8 < 16)
                        ? ((const uint4*)(feats_h + (size_t)nr * H))[c8]
                        : ((const uint4*)(nmbuf_h + (size_t)sl * M))[c8 - 16];
                }
                // current chunk row ids + old finalv (used at F next iteration)
                int nrC[4]; float fvC[4];
#pragma unroll
                for (int i = 0; i < 4; ++i) {
                    nrC[i] = (int)s_rnode[min(c0 + (quad << 2) + i, Pr - 1)];
                    fvC[i] = finalv[(size_t)nrC[i] * H + colw];
                }
                // F: phase2 MFMA for chunk k-1 (independent of D's chain)
                if (c0 > 0) {
                    const _Float16* nrow = s_NSh[nxt] + lm * NROW + (quad << 3);
#pragma unroll
                    for (int c = 0; c < 4; ++c)
                        accmP = __builtin_amdgcn_mfma_f32_16x16x32_f16(
                            *(const half8*)(nrow + (c << 5)), wbm[c], accmP, 0, 0, 0);
                    float na4[4];
#pragma unroll
                    for (int i = 0; i < 4; ++i) na4[i] = s_rna[nxt][(quad << 2) + i];
#pragma unroll
                    for (int i = 0; i < 4; ++i) {
                        const int r = (quad << 2) + i;
                        if (r < PcP)
                            nmbuf_h[(size_t)(sbP + r) * M + colw] =
                                (_Float16)(accmP[i] + nmb_c);
                    }
#pragma unroll
                    for (int i = 0; i < 4; ++i) {
                        const int r = (quad << 2) + i;
                        if (r < PcP)
                            finalv[(size_t)nrP[i] * H + colw] =
                                fvP[i] + nsvP[i] * na4[i];
                    }
                }
                // E: gate finalize chunk k (zredC from prev iter/prologue)
                if (sg == 0 && r16 < Pc) {
                    const float z = zredC + actb;
                    const float cnd = 1.0f / (1.0f + expf(-z));
                    const int nr = (int)s_rnode[c0 + r16];
                    const float ta = s_tact[nr];
                    const float na = (ta + cnd > 1.0f) ? (1.0f - ta) : cnd;
                    s_rna[cur][r16] = na;
                    s_tact[nr] = ta + na;
                }
                // D: phase1 MFMA chunk k: ns (K=256) + nm msg-half (K=128..256)
                floatx4 accn = {0.0f, 0.0f, 0.0f, 0.0f};
                floatx4 accm = {0.0f, 0.0f, 0.0f, 0.0f};
                {
                    const _Float16* xrow = s_Xh[cur] + lm * WROW + (quad << 3);
                    half8 a[8];
#pragma unroll
                    for (int c = 0; c < 8; ++c) a[c] = *(const half8*)(xrow + (c << 5));
#pragma unroll
                    for (int c = 0; c < 8; ++c)
                        accn = __builtin_amdgcn_mfma_f32_16x16x32_f16(
                            a[c], wbn[c], accn, 0, 0, 0);
#pragma unroll
                    for (int c = 4; c < 8; ++c)
                        accm = __builtin_amdgcn_mfma_f32_16x16x32_f16(
                            a[c], wbm[c], accm, 0, 0, 0);
                }
                float nsv[4];
#pragma unroll
                for (int i = 0; i < 4; ++i) {
                    const int r = (quad << 2) + i;
                    nsv[i] = fmaxf(accn[i] + nsb_c, 0.0f);
                    if (r < Pc) {
                        s_NSh[cur][r * NROW + colw] = (_Float16)nsv[i];
                        feats_h[(size_t)nrC[i] * H + colw] = (_Float16)nsv[i];
                    }
                }
                // rotate pipeline state
                accmP = accm;
#pragma unroll
                for (int i = 0; i < 4; ++i) { nsvP[i] = nsv[i]; fvP[i] = fvC[i]; nrP[i] = nrC[i]; }
                PcP = Pc; sbP = gbase + base + c0;
                zredC = zredN;
                bar_lds();               // publish Xh[nxt], NSh[cur], rna[cur]
            }
            // ---- epilogue: phase2 for last chunk ----
            {
                const int pb = ((Pr - 1) >> 4) & 1;
                const _Float16* nrow = s_NSh[pb] + lm * NROW + (quad << 3);
#pragma unroll
                for (int c = 0; c < 4; ++c)
                    accmP = __builtin_amdgcn_mfma_f32_16x16x32_f16(
                        *(const half8*)(nrow + (c << 5)), wbm[c], accmP, 0, 0, 0);
                float na4[4];
#pragma unroll
                for (int i = 0; i < 4; ++i) na4[i] = s_rna[pb][(quad << 2) + i];
#pragma unroll
                for (int i = 0; i < 4; ++i) {
                    const int r = (quad << 2) + i;
                    if (r < PcP)
                        nmbuf_h[(size_t)(sbP + r) * M + colw] =
                            (_Float16)(accmP[i] + nmb_c);
                }
#pragma unroll
                for (int i = 0; i < 4; ++i) {
                    const int r = (quad << 2) + i;
                    if (r < PcP)
                        finalv[(size_t)nrP[i] * H + colw] = fvP[i] + nsvP[i] * na4[i];
                }
            }
            base += Pr;
            __syncthreads();       // R7 (full): drain feats/nmbuf/finalv stores
        }

        // -------- enqueue (queue order via two-class prefix over flags) --------
        const bool pfa = (s_flag[t] & 1) != 0;
        const bool pfb = (s_flag[t] & 2) != 0;
        const unsigned long long mfa = __ballot(pfa);
        const unsigned long long mfb = __ballot(pfb);
        if (lane == 0) { s_wc[wid] = __popcll(mfa); s_wd[wid] = __popcll(mfb); }
        bar_lds();                                       // B3
        int TA = 0, TB = 0, preA = 0, preB = 0;
#pragma unroll
        for (int w = 0; w < 8; ++w) {
            TA += s_wc[w]; TB += s_wd[w];
            preA += (w < wid) ? s_wc[w] : 0;
            preB += (w < wid) ? s_wd[w] : 0;
        }
        const int T = TA + TB;
        if (T > 0) {
            const unsigned long long below = (1ull << lane) - 1ull;
            if (pfa) s_order[preA + __popcll(mfa & below)] = (short)t;
            if (pfb) s_order[TA + preB + __popcll(mfb & below)] = (short)(NT + t);
            bar_lds();                                   // B4
            for (int idx = t; idx < T * DEG; idx += NT) {
                const int e = (int)s_order[idx >> 4];
                const unsigned v = s_enq[e];
                const int nd = (int)(v & 0xffffu);
                const unsigned slot = v >> 16;
                const int q = tail + idx;
                if (q < QCAP)
                    s_q[q] = (unsigned)neighbors[nd * DEG + (idx & 15)] | (slot << 16);
            }
        }
        tail += DEG * T;
        gbase += T;
        head += W;
        bar_lds();                                       // B5 (LDS-only): s_q visible
    }

    // ---- readout (g/lg overlaid on dead mark region) ----
    if (t < H) {
        float g0 = 0, g1 = 0, g2 = 0, g3 = 0;
        for (int n = 0; n < NN; n += 4) {
            g0 += finalv[(n + 0) * H + t];
            g1 += finalv[(n + 1) * H + t];
            g2 += finalv[(n + 2) * H + t];
            g3 += finalv[(n + 3) * H + t];
        }
        s_g[t] = (g0 + g1) + (g2 + g3);
    }
    __syncthreads();
    if (t < PP * OUTF) {
        const int pp = t / OUTF, o = t % OUTF;
        float acc = dec_b[pp * OUTF + o];
        for (int h = 0; h < H; ++h) acc += s_g[h] * dec_w[(pp * H + h) * OUTF + o];
        s_lg[t] = acc;
    }
    __syncthreads();
    if (t < PP * OUTF) {
        const int pp = t / OUTF;
        float mx = -INFINITY;
        for (int o = 0; o < OUTF; ++o) mx = fmaxf(mx, s_lg[pp * OUTF + o]);
        float s = 0.0f;
        for (int o = 0; o < OUTF; ++o) s += expf(s_lg[pp * OUTF + o] - mx);
        out[t] = s_lg[t] - (mx + logf(s));
    }
}

extern "C" void kernel_launch(void* const* d_in, const int* in_sizes, int n_in,
                              void* d_out, int out_size, void* d_ws, size_t ws_size,
                              hipStream_t stream) {
    const float* xa        = (const float*)d_in[0];
    const float* fm        = (const float*)d_in[1];
    const int*   neighbors = (const int*)  d_in[2];
    const int*   nstart_p  = (const int*)  d_in[3];
    const float* enc_w     = (const float*)d_in[4];
    const float* enc_b     = (const float*)d_in[5];
    const float* ns_w      = (const float*)d_in[6];
    const float* ns_b      = (const float*)d_in[7];
    const float* nm_w      = (const float*)d_in[8];
    const float* nm_b      = (const float*)d_in[9];
    const float* act_w     = (const float*)d_in[10];
    const float* act_b     = (const float*)d_in[11];
    const float* dec_w     = (const float*)d_in[12];
    const float* dec_b     = (const float*)d_in[13];
    float* out = (float*)d_out;

    char* w = (char*)d_ws;
    _Float16* feats_h = (_Float16*)w;                 w += (size_t)NN * H * 2;
    float*    finalv  = (float*)w;                    w += (size_t)NN * H * 4;
    _Float16* nmbuf_h = (_Float16*)w;                 w += (size_t)NSLOT * M * 2;
    _Float16* wnsB    = (_Float16*)w;                 w += (size_t)128 * WROW * 2;
    _Float16* wnmB    = (_Float16*)w;                 w += (size_t)128 * WROW * 2;
    unsigned int* qpack = (unsigned int*)w;           // unused (LDS queue)

    init_kernel<<<NN, 128, 0, stream>>>(xa, fm, enc_w, enc_b, nstart_p,
                                        feats_h, finalv, nmbuf_h);
    pack_kernel<<<132, 256, 0, stream>>>(ns_w, nm_w, wnsB, wnmB);
    seq_kernel<<<1, NT, 0, stream>>>(neighbors, ns_b, nm_b,
                                     act_w, act_b, dec_w, dec_b, nstart_p,
                                     wnsB, wnmB,
                                     feats_h, finalv, nmbuf_h, qpack, out);
}

// Round 7
// 548.241 us; speedup vs baseline: 1.4366x; 1.1225x over previous
//
#include <hip/hip_runtime.h>
#include <math.h>

#define NN 1000
#define INF_ 32
#define H 128
#define M 128
#define DEG 16
#define PP 2
#define OUTF 10
#define MAXM (10 * NN)        // scan length; head <= MAXM
#define QCAP (MAXM + DEG)     // only entries < MAXM are ever read
#define NSLOT (MAXM + 128)    // nmbuf rows: nstart + total procs
#define NT 512
#define WQ (2 * NT)           // window size: 2 queue entries per thread
#define WROW 264              // padded halves per X/weight row (256+8)
#define NROW 136              // padded halves per NSh row (128+8)

typedef _Float16 half8 __attribute__((ext_vector_type(8)));
typedef float floatx4 __attribute__((ext_vector_type(4)));

// LDS-only barrier: publishes LDS writes without draining global (vmcnt) queue.
__device__ __forceinline__ void bar_lds() {
    asm volatile("s_waitcnt lgkmcnt(0)\n\ts_barrier" ::: "memory");
}

// ws: feats_h[NN*H] f16 | finalv[NN*H] f32 | nmbuf_h[NSLOT*M] f16
//     | wnsB f16 | wnmB f16 | (qpack region unused: queue lives in LDS)

__global__ __launch_bounds__(128)
void init_kernel(const float* __restrict__ xa, const float* __restrict__ fm,
                 const float* __restrict__ enc_w, const float* __restrict__ enc_b,
                 const int* __restrict__ nstart_p,
                 _Float16* __restrict__ feats_h, float* __restrict__ finalv,
                 _Float16* __restrict__ nmbuf_h) {
    int b = blockIdx.x, t = threadIdx.x;
    float acc = enc_b[t];
    const float* xr = xa + b * INF_;
#pragma unroll
    for (int k = 0; k < INF_; ++k) acc += xr[k] * enc_w[k * H + t];
    feats_h[b * H + t] = (_Float16)acc;     // same rounding point as before
    finalv[b * H + t] = 0.0f;
    if (b < nstart_p[0]) nmbuf_h[(size_t)b * M + t] = (_Float16)fm[b * M + t];
}

// Pack weights fp16 transposed [n][k] with +8 pad: wB[n*WROW+k] = w[k][n].
__global__ __launch_bounds__(256)
void pack_kernel(const float* __restrict__ ns_w, const float* __restrict__ nm_w,
                 _Float16* __restrict__ wnsB, _Float16* __restrict__ wnmB) {
    const int idx = blockIdx.x * 256 + threadIdx.x;   // 128*WROW
    if (idx >= 128 * WROW) return;
    const int n = idx / WROW, k = idx % WROW;
    wnsB[idx] = (k < 256) ? (_Float16)ns_w[k * H + n] : (_Float16)0.0f;
    wnmB[idx] = (k < 256) ? (_Float16)nm_w[k * M + n] : (_Float16)0.0f;
}

// Rank-decomposed sequential ACT loop; MFMA matvecs with REGISTER-RESIDENT
// weight B-fragments; LDS-only fine barriers; LDS message queue.
// R6 (VALU diet on R5's single-barrier pipeline):
//  - merged staging source: node/slot in one s_rns[2][WQ]; per-thread
//    loop-invariant rsoff + gsrc (feats/nmbuf share 256B row stride) ->
//    one ds_read_u16 + one load, no dual-address select per staging load.
//  - full-chunk (Pc==16) specialization: wave-uniform branch skips all
//    min-clamps and r<Pc store guards on the ~85% common path.
//  - finalv via global atomicAdd f32 (RN add == old v_mul+v_add bitwise);
//    removes fv loads + fvP pipeline state.
__global__ __launch_bounds__(NT, 1)
void seq_kernel(const int* __restrict__ neighbors,
                const float* __restrict__ ns_b, const float* __restrict__ nm_b,
                const float* __restrict__ act_w, const float* __restrict__ act_b,
                const float* __restrict__ dec_w, const float* __restrict__ dec_b,
                const int* __restrict__ nstart_p,
                const _Float16* __restrict__ wnsB, const _Float16* __restrict__ wnmB,
                _Float16* __restrict__ feats_h, float* __restrict__ finalv,
                _Float16* __restrict__ nmbuf_h, unsigned int* __restrict__ qpack_unused,
                float* __restrict__ out) {
    __shared__ __align__(16) _Float16 s_Xh[2][16 * WROW];   // 16896 B
    __shared__ __align__(16) _Float16 s_NSh[2][16 * NROW];  // 8704 B
    __shared__ unsigned int s_q[QCAP];                      // 40064 B (LDS queue)
    __shared__ float s_tact[NN];                            // 4000 B
    __shared__ int   s_mark[NN];                            // 4000 B (order/readout overlay)
    __shared__ float s_actw[H + M];
    __shared__ float s_nsb[H];
    __shared__ float s_nmb[M];
    __shared__ float s_rna[2][16];
    __shared__ unsigned short s_rns[2 * WQ];                // [0]=node, [WQ]=slot, rank order
    __shared__ unsigned int  s_enq[WQ];                     // node|newslot<<16 per entry
    __shared__ unsigned char s_flag[NT];                    // bit0: entry t, bit1: entry 512+t
    __shared__ int s_wc[8], s_wd[8];
    __shared__ int s_cnt;

    unsigned short* const s_rnode = s_rns;
    unsigned short* const s_rslot = s_rns + WQ;
    short* s_order = (short*)s_mark;                     // overlay: mark[0..511] = 1024 shorts
    float* s_g  = (float*)(s_mark + 512);                // overlay: readout only
    float* s_lg = (float*)(s_mark + 512 + 128);

    const int t = threadIdx.x;
    const int lane = t & 63, wid = t >> 6;
    const int quad = lane >> 4, lm = lane & 15;
    const int colw = (wid << 4) + lm;                    // this thread's output col
    const int sg = t & 31;                               // gate sub-lane
    const int r16 = t >> 5, c8 = t & 31;                 // staging coords (16x32)
    const int nstart = nstart_p[0];
    // loop-invariant staging source (feats row stride == nmbuf row stride == 128 halves)
    const int rsoff = (c8 < 16) ? 0 : WQ;
    const _Float16* const gsrc = (c8 < 16) ? (feats_h + c8 * 8)
                                           : (nmbuf_h + (c8 - 16) * 8);

    // ---- one-time: weight B-fragments into registers (loop-invariant) ----
    half8 wbn[8], wbm[8];
#pragma unroll
    for (int c = 0; c < 8; ++c) {
        wbn[c] = *(const half8*)(wnsB + (size_t)colw * WROW + (c << 5) + (quad << 3));
        wbm[c] = *(const half8*)(wnmB + (size_t)colw * WROW + (c << 5) + (quad << 3));
    }

    for (int i = t; i < NN; i += NT) { s_tact[i] = 0.0f; s_mark[i] = 0x7fffffff; }
    for (int i = t; i < nstart; i += NT) s_q[i] = (unsigned)i | ((unsigned)i << 16);
    if (t < H + M) s_actw[t] = act_w[t];
    if (t < H) { s_nsb[t] = ns_b[t]; s_nmb[t] = nm_b[t]; }
    const float actb = act_b[0];
    __syncthreads();
    const float nsb_c = s_nsb[colw];
    const float nmb_c = s_nmb[colw];
    float aw[8];
#pragma unroll
    for (int j = 0; j < 8; ++j) aw[j] = s_actw[sg * 8 + j];

    int head = 0, tail = nstart, gbase = nstart;
    for (;;) {
        const int lim = min(tail, MAXM);
        if (head >= lim) break;
        const int W = min(WQ, lim - head);

        // ---- classify both entries; clear flags; repair order-overlaid mark ----
        int nodeA = 0, slotA = 0; bool remA = false;
        int nodeB = 0, slotB = 0; bool remB = false;
        if (t < W) {
            const unsigned v = s_q[head + t];
            nodeA = (int)(v & 0xffffu);
            slotA = (int)(v >> 16);
            remA = (s_tact[nodeA] <= 1.0f - 1e-7f);
        }
        if (NT + t < W) {
            const unsigned v = s_q[head + NT + t];
            nodeB = (int)(v & 0xffffu);
            slotB = (int)(v >> 16);
            remB = (s_tact[nodeB] <= 1.0f - 1e-7f);
        }
        s_flag[t] = 0;
        s_mark[t] = 0x7fffffff;                          // repair overlay (t<512 region)
        bar_lds();                                       // B1

        // ---------------- rank rounds ----------------
        int base = 0;
        for (;;) {
            const bool rem2a = remA && (s_tact[nodeA] <= 1.0f - 1e-7f);
            const bool rem2b = remB && (s_tact[nodeB] <= 1.0f - 1e-7f);
            if (rem2a) atomicMin(&s_mark[nodeA], t);
            if (rem2b) atomicMin(&s_mark[nodeB], NT + t);
            if (t == 0) s_cnt = 0;
            bar_lds();                                   // R1
            const bool winA = rem2a && (s_mark[nodeA] == t);
            const bool winB = rem2b && (s_mark[nodeB] == NT + t);
            const unsigned long long ma = __ballot(winA);
            const unsigned long long mb = __ballot(winB);
            const int ca = __popcll(ma), cb = __popcll(mb);
            int wbase = 0;
            if (lane == 0 && (ca + cb)) wbase = atomicAdd(&s_cnt, ca + cb);
            wbase = __shfl(wbase, 0, 64);
            const unsigned long long below = (1ull << lane) - 1ull;
            if (winA) {
                const int wrank = wbase + __popcll(ma & below);
                s_rnode[wrank] = (unsigned short)nodeA;
                s_rslot[wrank] = (unsigned short)slotA;
                s_enq[t] = (unsigned)nodeA | ((unsigned)(gbase + base + wrank) << 16);
                s_flag[t] |= 1;
            }
            if (winB) {
                const int wrank = wbase + ca + __popcll(mb & below);
                s_rnode[wrank] = (unsigned short)nodeB;
                s_rslot[wrank] = (unsigned short)slotB;
                s_enq[NT + t] = (unsigned)nodeB | ((unsigned)(gbase + base + wrank) << 16);
                s_flag[t] |= 2;
            }
            remA = rem2a && !winA;
            remB = rem2b && !winB;
            bar_lds();                                   // R3: rnode/rslot/cnt ready
            // mark reset: barrier-separated from win-check reads (race-free);
            // next atomicMin use is after R7 (full sync).
            if (rem2a) s_mark[nodeA] = 0x7fffffff;
            if (rem2b) s_mark[nodeB] = 0x7fffffff;
            const int Pr = s_cnt;
            if (Pr == 0) break;

            // ================= single-barrier pipelined chunk loop =================
            // ---- prologue: chunk 0 ----
            uint4 px = *(const uint4*)(gsrc + (size_t)s_rns[rsoff + min(r16, Pr - 1)] * 128);
            *(uint4*)(s_Xh[0] + r16 * WROW + (c8 << 3)) = px;
            float zredC;
            {
                const half8 hv = *(const half8*)&px;
                float p = 0.0f;
#pragma unroll
                for (int j = 0; j < 8; ++j) p += (float)hv[j] * aw[j];
#pragma unroll
                for (int off = 16; off > 0; off >>= 1) p += __shfl_down(p, off, 32);
                zredC = p;                               // valid in sg==0
            }
            if (Pr > 16)                                 // prefetch chunk 1
                px = *(const uint4*)(gsrc + (size_t)s_rns[rsoff + min(16 + r16, Pr - 1)] * 128);
            bar_lds();                                   // publish Xh[0]

            floatx4 accmP = {0.0f, 0.0f, 0.0f, 0.0f};
            float nsvP[4] = {0, 0, 0, 0};
            int   nrP[4] = {0, 0, 0, 0};
            int PcP = 0, sbP = 0;

            for (int c0 = 0; c0 < Pr; c0 += 16) {
                const int k = c0 >> 4;
                const int cur = k & 1, nxt = cur ^ 1;
                const int rem = Pr - c0;
                const bool fullC = rem >= 16;
                const int Pc = fullC ? 16 : rem;
                const bool hasnext = rem > 16;
                // stage chunk k+1 from px; gate-reduce it
                float zredN = 0.0f;
                if (hasnext) {
                    *(uint4*)(s_Xh[nxt] + r16 * WROW + (c8 << 3)) = px;
                    const half8 hv = *(const half8*)&px;
                    float p = 0.0f;
#pragma unroll
                    for (int j = 0; j < 8; ++j) p += (float)hv[j] * aw[j];
#pragma unroll
                    for (int off = 16; off > 0; off >>= 1) p += __shfl_down(p, off, 32);
                    zredN = p;
                }
                // prefetch chunk k+2
                if (rem > 32)
                    px = *(const uint4*)(gsrc + (size_t)s_rns[rsoff + min(c0 + 32 + r16, Pr - 1)] * 128);
                // current chunk row ids
                int nrC[4];
                if (fullC) {
#pragma unroll
                    for (int i = 0; i < 4; ++i)
                        nrC[i] = (int)s_rnode[c0 + (quad << 2) + i];
                } else {
#pragma unroll
                    for (int i = 0; i < 4; ++i)
                        nrC[i] = (int)s_rnode[min(c0 + (quad << 2) + i, Pr - 1)];
                }
                // F: phase2 MFMA for chunk k-1 (independent of D's chain)
                if (c0 > 0) {
                    const _Float16* nrow = s_NSh[nxt] + lm * NROW + (quad << 3);
#pragma unroll
                    for (int c = 0; c < 4; ++c)
                        accmP = __builtin_amdgcn_mfma_f32_16x16x32_f16(
                            *(const half8*)(nrow + (c << 5)), wbm[c], accmP, 0, 0, 0);
                    float na4[4];
#pragma unroll
                    for (int i = 0; i < 4; ++i) na4[i] = s_rna[nxt][(quad << 2) + i];
                    if (PcP == 16) {
#pragma unroll
                        for (int i = 0; i < 4; ++i)
                            nmbuf_h[(size_t)(sbP + (quad << 2) + i) * M + colw] =
                                (_Float16)(accmP[i] + nmb_c);
#pragma unroll
                        for (int i = 0; i < 4; ++i)
                            atomicAdd(finalv + (size_t)nrP[i] * H + colw,
                                      nsvP[i] * na4[i]);
                    } else {
#pragma unroll
                        for (int i = 0; i < 4; ++i) {
                            const int r = (quad << 2) + i;
                            if (r < PcP) {
                                nmbuf_h[(size_t)(sbP + r) * M + colw] =
                                    (_Float16)(accmP[i] + nmb_c);
                                atomicAdd(finalv + (size_t)nrP[i] * H + colw,
                                          nsvP[i] * na4[i]);
                            }
                        }
                    }
                }
                // E: gate finalize chunk k (zredC from prev iter/prologue)
                if (sg == 0 && r16 < Pc) {
                    const float z = zredC + actb;
                    const float cnd = 1.0f / (1.0f + expf(-z));
                    const int nr = (int)s_rnode[c0 + r16];
                    const float ta = s_tact[nr];
                    const float na = (ta + cnd > 1.0f) ? (1.0f - ta) : cnd;
                    s_rna[cur][r16] = na;
                    s_tact[nr] = ta + na;
                }
                // D: phase1 MFMA chunk k: ns (K=256) + nm msg-half (K=128..256)
                floatx4 accn = {0.0f, 0.0f, 0.0f, 0.0f};
                floatx4 accm = {0.0f, 0.0f, 0.0f, 0.0f};
                {
                    const _Float16* xrow = s_Xh[cur] + lm * WROW + (quad << 3);
                    half8 a[8];
#pragma unroll
                    for (int c = 0; c < 8; ++c) a[c] = *(const half8*)(xrow + (c << 5));
#pragma unroll
                    for (int c = 0; c < 8; ++c)
                        accn = __builtin_amdgcn_mfma_f32_16x16x32_f16(
                            a[c], wbn[c], accn, 0, 0, 0);
#pragma unroll
                    for (int c = 4; c < 8; ++c)
                        accm = __builtin_amdgcn_mfma_f32_16x16x32_f16(
                            a[c], wbm[c], accm, 0, 0, 0);
                }
                float nsv[4];
#pragma unroll
                for (int i = 0; i < 4; ++i) nsv[i] = fmaxf(accn[i] + nsb_c, 0.0f);
                if (fullC) {
#pragma unroll
                    for (int i = 0; i < 4; ++i) {
                        const int r = (quad << 2) + i;
                        s_NSh[cur][r * NROW + colw] = (_Float16)nsv[i];
                        feats_h[(size_t)nrC[i] * H + colw] = (_Float16)nsv[i];
                    }
                } else {
#pragma unroll
                    for (int i = 0; i < 4; ++i) {
                        const int r = (quad << 2) + i;
                        if (r < Pc) {
                            s_NSh[cur][r * NROW + colw] = (_Float16)nsv[i];
                            feats_h[(size_t)nrC[i] * H + colw] = (_Float16)nsv[i];
                        }
                    }
                }
                // rotate pipeline state
                accmP = accm;
#pragma unroll
                for (int i = 0; i < 4; ++i) { nsvP[i] = nsv[i]; nrP[i] = nrC[i]; }
                PcP = Pc; sbP = gbase + base + c0;
                zredC = zredN;
                bar_lds();               // publish Xh[nxt], NSh[cur], rna[cur]
            }
            // ---- epilogue: phase2 for last chunk ----
            {
                const int pb = ((Pr - 1) >> 4) & 1;
                const _Float16* nrow = s_NSh[pb] + lm * NROW + (quad << 3);
#pragma unroll
                for (int c = 0; c < 4; ++c)
                    accmP = __builtin_amdgcn_mfma_f32_16x16x32_f16(
                        *(const half8*)(nrow + (c << 5)), wbm[c], accmP, 0, 0, 0);
                float na4[4];
#pragma unroll
                for (int i = 0; i < 4; ++i) na4[i] = s_rna[pb][(quad << 2) + i];
#pragma unroll
                for (int i = 0; i < 4; ++i) {
                    const int r = (quad << 2) + i;
                    if (r < PcP) {
                        nmbuf_h[(size_t)(sbP + r) * M + colw] =
                            (_Float16)(accmP[i] + nmb_c);
                        atomicAdd(finalv + (size_t)nrP[i] * H + colw,
                                  nsvP[i] * na4[i]);
                    }
                }
            }
            base += Pr;
            __syncthreads();       // R7 (full): drain feats/nmbuf/finalv stores
        }

        // -------- enqueue (queue order via two-class prefix over flags) --------
        const bool pfa = (s_flag[t] & 1) != 0;
        const bool pfb = (s_flag[t] & 2) != 0;
        const unsigned long long mfa = __ballot(pfa);
        const unsigned long long mfb = __ballot(pfb);
        if (lane == 0) { s_wc[wid] = __popcll(mfa); s_wd[wid] = __popcll(mfb); }
        bar_lds();                                       // B3
        int TA = 0, TB = 0, preA = 0, preB = 0;
#pragma unroll
        for (int w = 0; w < 8; ++w) {
            TA += s_wc[w]; TB += s_wd[w];
            preA += (w < wid) ? s_wc[w] : 0;
            preB += (w < wid) ? s_wd[w] : 0;
        }
        const int T = TA + TB;
        if (T > 0) {
            const unsigned long long below = (1ull << lane) - 1ull;
            if (pfa) s_order[preA + __popcll(mfa & below)] = (short)t;
            if (pfb) s_order[TA + preB + __popcll(mfb & below)] = (short)(NT + t);
            bar_lds();                                   // B4
            for (int idx = t; idx < T * DEG; idx += NT) {
                const int e = (int)s_order[idx >> 4];
                const unsigned v = s_enq[e];
                const int nd = (int)(v & 0xffffu);
                const unsigned slot = v >> 16;
                const int q = tail + idx;
                if (q < QCAP)
                    s_q[q] = (unsigned)neighbors[nd * DEG + (idx & 15)] | (slot << 16);
            }
        }
        tail += DEG * T;
        gbase += T;
        head += W;
        bar_lds();                                       // B5 (LDS-only): s_q visible
    }

    // ---- readout (g/lg overlaid on dead mark region) ----
    if (t < H) {
        float g0 = 0, g1 = 0, g2 = 0, g3 = 0;
        for (int n = 0; n < NN; n += 4) {
            g0 += finalv[(n + 0) * H + t];
            g1 += finalv[(n + 1) * H + t];
            g2 += finalv[(n + 2) * H + t];
            g3 += finalv[(n + 3) * H + t];
        }
        s_g[t] = (g0 + g1) + (g2 + g3);
    }
    __syncthreads();
    if (t < PP * OUTF) {
        const int pp = t / OUTF, o = t % OUTF;
        float acc = dec_b[pp * OUTF + o];
        for (int h = 0; h < H; ++h) acc += s_g[h] * dec_w[(pp * H + h) * OUTF + o];
        s_lg[t] = acc;
    }
    __syncthreads();
    if (t < PP * OUTF) {
        const int pp = t / OUTF;
        float mx = -INFINITY;
        for (int o = 0; o < OUTF; ++o) mx = fmaxf(mx, s_lg[pp * OUTF + o]);
        float s = 0.0f;
        for (int o = 0; o < OUTF; ++o) s += expf(s_lg[pp * OUTF + o] - mx);
        out[t] = s_lg[t] - (mx + logf(s));
    }
}

extern "C" void kernel_launch(void* const* d_in, const int* in_sizes, int n_in,
                              void* d_out, int out_size, void* d_ws, size_t ws_size,
                              hipStream_t stream) {
    const float* xa        = (const float*)d_in[0];
    const float* fm        = (const float*)d_in[1];
    const int*   neighbors = (const int*)  d_in[2];
    const int*   nstart_p  = (const int*)  d_in[3];
    const float* enc_w     = (const float*)d_in[4];
    const float* enc_b     = (const float*)d_in[5];
    const float* ns_w      = (const float*)d_in[6];
    const float* ns_b      = (const float*)d_in[7];
    const float* nm_w      = (const float*)d_in[8];
    const float* nm_b      = (const float*)d_in[9];
    const float* act_w     = (const float*)d_in[10];
    const float* act_b     = (const float*)d_in[11];
    const float* dec_w     = (const float*)d_in[12];
    const float* dec_b     = (const float*)d_in[13];
    float* out = (float*)d_out;

    char* w = (char*)d_ws;
    _Float16* feats_h = (_Float16*)w;                 w += (size_t)NN * H * 2;
    float*    finalv  = (float*)w;                    w += (size_t)NN * H * 4;
    _Float16* nmbuf_h = (_Float16*)w;                 w += (size_t)NSLOT * M * 2;
    _Float16* wnsB    = (_Float16*)w;                 w += (size_t)128 * WROW * 2;
    _Float16* wnmB    = (_Float16*)w;                 w += (size_t)128 * WROW * 2;
    unsigned int* qpack = (unsigned int*)w;           // unused (LDS queue)

    init_kernel<<<NN, 128, 0, stream>>>(xa, fm, enc_w, enc_b, nstart_p,
                                        feats_h, finalv, nmbuf_h);
    pack_kernel<<<132, 256, 0, stream>>>(ns_w, nm_w, wnsB, wnmB);
    seq_kernel<<<1, NT, 0, stream>>>(neighbors, ns_b, nm_b,
                                     act_w, act_b, dec_w, dec_b, nstart_p,
                                     wnsB, wnmB,
                                     feats_h, finalv, nmbuf_h, qpack, out);
}